// Round 11
// baseline (222.444 us; speedup 1.0000x reference)
//
#include <hip/hip_runtime.h>

// B=16, Q=512, P=2048, D=256, H=8, DH=32
#define BB 16
#define QQ 512
#define PP 2048
#define DD 256
#define HH 8
#define DH 32

typedef __attribute__((ext_vector_type(8))) short short8;
typedef __attribute__((ext_vector_type(4))) float f32x4;

static __device__ __forceinline__ unsigned short f2bf(float f) {
  union { float f; unsigned u; } v; v.f = f;
  unsigned u = v.u;
  unsigned r = (u + 0x7FFFu + ((u >> 16) & 1u)) >> 16;  // RNE
  return (unsigned short)r;
}

static __device__ __forceinline__ short8 load_f32x8_bf16(const float* p) {
  const float4* p4 = (const float4*)p;
  float4 a = p4[0], b = p4[1];
  short8 r;
  r[0] = (short)f2bf(a.x); r[1] = (short)f2bf(a.y);
  r[2] = (short)f2bf(a.z); r[3] = (short)f2bf(a.w);
  r[4] = (short)f2bf(b.x); r[5] = (short)f2bf(b.y);
  r[6] = (short)f2bf(b.z); r[7] = (short)f2bf(b.w);
  return r;
}

// ---------------- Kernel 0a: pack in_proj_w (768x256 f32) -> bf16 ----------------
__global__ __launch_bounds__(256) void pack_w_kernel(const float* __restrict__ w,
                                                     unsigned short* __restrict__ wb, int n8) {
  int t = blockIdx.x * 256 + threadIdx.x;
  if (t < n8) {
    short8 v = load_f32x8_bf16(w + (size_t)t * 8);
    *(short8*)(wb + (size_t)t * 8) = v;
  }
}

// ---------------- Kernel 0b: pack mask (int32) -> 1 bit/key ----------------
// mask64[(b*Q+q)*32 + p/64], bit (p&63) set = masked-out.
__global__ __launch_bounds__(256) void pack_mask_kernel(const int* __restrict__ mask,
                                                        unsigned long long* __restrict__ mask64) {
  int wave = (blockIdx.x * 256 + threadIdx.x) >> 6;  // 8192 waves
  int lane = threadIdx.x & 63;
  const int NG = BB * QQ * (PP / 64);  // 262144 groups
  for (int g = wave; g < NG; g += 8192) {
    int v = mask[(size_t)g * 64 + lane];
    unsigned long long bits = __ballot(v != 0);
    if (lane == 0) mask64[g] = bits;
  }
}

// ---------------- Kernel 1: input projections (round-9 exact, PASSED) ----------------
template <int NF>
__global__ __launch_bounds__(512) void proj_kernel(
    const float* __restrict__ in, const unsigned short* __restrict__ wb,
    const float* __restrict__ bias,
    unsigned short* __restrict__ out0, unsigned short* __restrict__ out1,
    int mode) {
  int tid = threadIdx.x;
  int wid = tid >> 6, lane = tid & 63;
  int wm = wid >> 2, wn = wid & 3;
  int lr = lane & 15, lk = lane >> 4;
  int m0 = blockIdx.x * 64 + wm * 32;
  int n0 = wn * NF * 16;

  f32x4 acc[2][NF] = {};
  for (int k0 = 0; k0 < 256; k0 += 32) {
    short8 af[2];
    af[0] = load_f32x8_bf16(in + (size_t)(m0 + lr) * 256 + k0 + lk * 8);
    af[1] = load_f32x8_bf16(in + (size_t)(m0 + 16 + lr) * 256 + k0 + lk * 8);
#pragma unroll
    for (int j = 0; j < NF; j++) {
      short8 bfr = *(const short8*)(wb + (size_t)(n0 + j * 16 + lr) * 256 + k0 + lk * 8);
      acc[0][j] = __builtin_amdgcn_mfma_f32_16x16x32_bf16(af[0], bfr, acc[0][j], 0, 0, 0);
      acc[1][j] = __builtin_amdgcn_mfma_f32_16x16x32_bf16(af[1], bfr, acc[1][j], 0, 0, 0);
    }
  }
#pragma unroll
  for (int i = 0; i < 2; i++)
#pragma unroll
    for (int j = 0; j < NF; j++) {
      int n = n0 + j * 16 + lr;  // D col = lane&15
      float bv = bias[n];
      if (mode == 1 && n >= 256) {
        // V path: rows m = m0+i*16+lk*4+{0..3} are 4 consecutive p -> one 8B store
        int n2 = n - 256;
        int p0i = m0 + i * 16 + lk * 4;
        int b = p0i >> 11;
        int p = p0i & 2047;
        unsigned long long w = 0;
#pragma unroll
        for (int r = 0; r < 4; r++)
          w |= (unsigned long long)f2bf(acc[i][j][r] + bv) << (r * 16);
        *(unsigned long long*)(out1 + ((size_t)(b * 8 + (n2 >> 5)) * 32 + (n2 & 31)) * 2048 + p) = w;
      } else {
#pragma unroll
        for (int r = 0; r < 4; r++) {
          int m = m0 + i * 16 + lk * 4 + r;  // D row = 4*(lane>>4)+r
          unsigned short o = f2bf(acc[i][j][r] + bv);
          if (mode == 0) {
            int b = m >> 9, q = m & 511;
            out0[(((size_t)(b * 8 + (n >> 5)) * 512 + q) * 32) + (n & 31)] = o;
          } else {
            int b = m >> 11, p = m & 2047;
            out0[(((size_t)(b * 8 + (n >> 5)) * 2048 + p) * 32) + (n & 31)] = o;
          }
        }
      }
    }
}

// ---------------- Kernel 2: attention, no-max softmax, KVBLK=128, V pre-barrier ----------------
// Round-9 numerics byte-identical; __syncthreads kept (empirically required).
// Changes: (a) 128 keys/iteration -> 16 barriers instead of 32; (b) V fragments
// loaded into registers BEFORE the barrier, so the barrier's vmcnt(0) drain
// overlaps V latency with the exp phase instead of exposing it inside PV.
__global__ __launch_bounds__(256) void attn_kernel(
    const unsigned short* __restrict__ Qb, const unsigned short* __restrict__ Kb,
    const unsigned short* __restrict__ Vt, const unsigned long long* __restrict__ mask64,
    unsigned short* __restrict__ Ob) {
  __shared__ unsigned short Plds[4][16][136];  // per-wave P tile, 128 keys + pad
  int bid = blockIdx.x;
  int xcd = bid & 7, sg = bid >> 3;
  int bh = xcd * 16 + (sg >> 3);
  int qt = sg & 7;
  int b = bh >> 3, h = bh & 7;
  int tid = threadIdx.x, wid = tid >> 6, lane = tid & 63;
  int lr = lane & 15, lk = lane >> 4;
  int qbase = qt * 64 + wid * 16;
  const float scale = 0.17677669529663687f;  // 1/sqrt(32)

  short8 qa = *(const short8*)(Qb + ((size_t)bh * QQ + qbase + lr) * 32 + lk * 8);

  float psum[4] = {0.f, 0.f, 0.f, 0.f};  // row lk*4+r, this lane's keys {f*16+lr}
  f32x4 acc[2] = {};

  const unsigned short* Kbase = Kb + (size_t)bh * PP * 32;
  const unsigned short* Vbase = Vt + (size_t)bh * 32 * PP;
  const unsigned long long* mbase = mask64 + ((size_t)b * QQ + qbase) * (PP / 64);

  for (int p0 = 0; p0 < PP; p0 += 128) {
    // S = Q*K^T for 16 q x 128 keys (8 MFMAs)
    f32x4 s[8];
#pragma unroll
    for (int f = 0; f < 8; f++) {
      short8 kb = *(const short8*)(Kbase + (size_t)(p0 + f * 16 + lr) * 32 + lk * 8);
      f32x4 z = {};
      s[f] = __builtin_amdgcn_mfma_f32_16x16x32_bf16(qa, kb, z, 0, 0, 0);
    }
    // V fragments for this chunk -> registers (in flight during exp + barrier)
    short8 vb[4][2];
#pragma unroll
    for (int kc = 0; kc < 4; kc++)
#pragma unroll
      for (int dhf = 0; dhf < 2; dhf++)
        vb[kc][dhf] = *(const short8*)(Vbase + (size_t)(dhf * 16 + lr) * PP + p0 + kc * 32 + lk * 8);
    // exp + psum + P writes, in two 64-key halves (caps live mask VGPRs)
#pragma unroll
    for (int half = 0; half < 2; half++) {
      unsigned long long mw[4];
#pragma unroll
      for (int r = 0; r < 4; r++)
        mw[r] = mbase[(size_t)(lk * 4 + r) * (PP / 64) + (p0 >> 6) + half];
#pragma unroll
      for (int f2 = 0; f2 < 4; f2++) {
        int f = half * 4 + f2;
#pragma unroll
        for (int r = 0; r < 4; r++) {
          int masked = (int)((mw[r] >> (f2 * 16 + lr)) & 1ull);
          float p = __expf(s[f][r] * scale);
          p = masked ? 0.f : p;
          psum[r] += p;
          Plds[wid][lk * 4 + r][f * 16 + lr] = f2bf(p);
        }
      }
    }
    __syncthreads();  // proven-required ordering; also drains V loads usefully
    // PV: acc += P[16x128] * V[128x32] — pure LDS reads + MFMA
#pragma unroll
    for (int kc = 0; kc < 4; kc++) {
      short8 pa = *(const short8*)&Plds[wid][lr][kc * 32 + lk * 8];
#pragma unroll
      for (int dhf = 0; dhf < 2; dhf++)
        acc[dhf] = __builtin_amdgcn_mfma_f32_16x16x32_bf16(pa, vb[kc][dhf], acc[dhf], 0, 0, 0);
    }
  }
  // single final reduce: psum[r] over the 16 lr lanes (width-16 butterfly)
#pragma unroll
  for (int r = 0; r < 4; r++) {
#pragma unroll
    for (int d = 1; d < 16; d <<= 1) psum[r] += __shfl_xor(psum[r], d, 64);
  }
  // normalize + write O bf16 [B,Q,256]
#pragma unroll
  for (int dhf = 0; dhf < 2; dhf++)
#pragma unroll
    for (int r = 0; r < 4; r++) {
      int q = qbase + lk * 4 + r;
      float o = acc[dhf][r] / psum[r];
      Ob[((size_t)b * QQ + q) * 256 + h * 32 + dhf * 16 + lr] = f2bf(o);
    }
}

// ---------------- Kernel 3: out-proj + bias + residual + LayerNorm (round-9 exact) ----------------
__global__ __launch_bounds__(256) void outln_kernel(
    const unsigned short* __restrict__ Ob, const float* __restrict__ out_w,
    const float* __restrict__ out_b, const float* __restrict__ queries,
    const float* __restrict__ ln_g, const float* __restrict__ ln_b,
    float* __restrict__ out) {
  __shared__ float rowbuf[16][260];
  int mt = blockIdx.x;
  int tid = threadIdx.x, wid = tid >> 6, lane = tid & 63;
  int lr = lane & 15, lk = lane >> 4;
  int m0 = mt * 16;
  f32x4 acc[4] = {};
  for (int k0 = 0; k0 < 256; k0 += 32) {
    short8 af = *(const short8*)(Ob + (size_t)(m0 + lr) * 256 + k0 + lk * 8);
#pragma unroll
    for (int j = 0; j < 4; j++) {
      short8 bfr = load_f32x8_bf16(out_w + (size_t)(wid * 64 + j * 16 + lr) * 256 + k0 + lk * 8);
      acc[j] = __builtin_amdgcn_mfma_f32_16x16x32_bf16(af, bfr, acc[j], 0, 0, 0);
    }
  }
#pragma unroll
  for (int j = 0; j < 4; j++) {
    int n = wid * 64 + j * 16 + lr;
    float bv = out_b[n];
#pragma unroll
    for (int r = 0; r < 4; r++) {
      int m = m0 + lk * 4 + r;
      rowbuf[lk * 4 + r][n] = acc[j][r] + bv + queries[(size_t)m * 256 + n];
    }
  }
  __syncthreads();
  int row = tid >> 4, seg = tid & 15;
  float s1 = 0.f, s2 = 0.f, vals[16];
#pragma unroll
  for (int c = 0; c < 16; c++) {
    float v = rowbuf[row][seg * 16 + c];
    vals[c] = v; s1 += v; s2 += v * v;
  }
#pragma unroll
  for (int d = 1; d < 16; d <<= 1) {
    s1 += __shfl_xor(s1, d, 64);
    s2 += __shfl_xor(s2, d, 64);
  }
  float mean = s1 * (1.f / 256.f);
  float var = s2 * (1.f / 256.f) - mean * mean;
  float rstd = rsqrtf(var + 1e-5f);
  int m = m0 + row;
#pragma unroll
  for (int c = 0; c < 16; c++) {
    int col = seg * 16 + c;
    out[(size_t)m * 256 + col] = (vals[c] - mean) * rstd * ln_g[col] + ln_b[col];
  }
}

extern "C" void kernel_launch(void* const* d_in, const int* in_sizes, int n_in,
                              void* d_out, int out_size, void* d_ws, size_t ws_size,
                              hipStream_t stream) {
  const float* sources  = (const float*)d_in[0];
  const float* queries  = (const float*)d_in[1];
  const int* attn_mask  = (const int*)d_in[2];
  const float* in_proj_w = (const float*)d_in[3];
  const float* in_proj_b = (const float*)d_in[4];
  const float* out_w = (const float*)d_in[5];
  const float* out_b = (const float*)d_in[6];
  const float* ln_g  = (const float*)d_in[7];
  const float* ln_b  = (const float*)d_in[8];
  float* out = (float*)d_out;

  // workspace layout (shorts) — identical footprint to rounds 3/6/8/9 (passed):
  unsigned short* base = (unsigned short*)d_ws;
  unsigned long long* mask64 = (unsigned long long*)d_ws;          // 2 MB
  unsigned short* Qb = base + 1048576;                             // [B,H,Q,32]
  unsigned short* Kb = Qb + 2097152;                               // [B,H,P,32]
  unsigned short* Vt = Kb + 8388608;                               // [B,H,32,P]
  unsigned short* Ob = Vt + 8388608;                               // [B,Q,256]
  unsigned short* Wb = Ob + 2097152;                               // in_proj_w bf16

  dim3 b256(256), b512(512);
  pack_w_kernel<<<96, b256, 0, stream>>>(in_proj_w, Wb, 768 * 256 / 8);
  pack_mask_kernel<<<2048, b256, 0, stream>>>(attn_mask, mask64);
  proj_kernel<4><<<128, b512, 0, stream>>>(queries, Wb, in_proj_b, Qb, nullptr, 0);
  proj_kernel<8><<<512, b512, 0, stream>>>(sources, Wb + 256 * 256, in_proj_b + 256, Kb, Vt, 1);
  attn_kernel<<<1024, b256, 0, stream>>>(Qb, Kb, Vt, mask64, Ob);
  outln_kernel<<<512, b256, 0, stream>>>(Ob, out_w, out_b, queries, ln_g, ln_b, out);
}

// Round 13
// 222.244 us; speedup vs baseline: 1.0009x; 1.0009x over previous
//
#include <hip/hip_runtime.h>

// B=16, Q=512, P=2048, D=256, H=8, DH=32
#define BB 16
#define QQ 512
#define PP 2048
#define DD 256
#define HH 8
#define DH 32

typedef __attribute__((ext_vector_type(8))) short short8;
typedef __attribute__((ext_vector_type(4))) float f32x4;

static __device__ __forceinline__ unsigned short f2bf(float f) {
  union { float f; unsigned u; } v; v.f = f;
  unsigned u = v.u;
  unsigned r = (u + 0x7FFFu + ((u >> 16) & 1u)) >> 16;  // RNE
  return (unsigned short)r;
}

static __device__ __forceinline__ short8 load_f32x8_bf16(const float* p) {
  const float4* p4 = (const float4*)p;
  float4 a = p4[0], b = p4[1];
  short8 r;
  r[0] = (short)f2bf(a.x); r[1] = (short)f2bf(a.y);
  r[2] = (short)f2bf(a.z); r[3] = (short)f2bf(a.w);
  r[4] = (short)f2bf(b.x); r[5] = (short)f2bf(b.y);
  r[6] = (short)f2bf(b.z); r[7] = (short)f2bf(b.w);
  return r;
}

// ---------------- Kernel 0a: pack in_proj_w (768x256 f32) -> bf16 ----------------
__global__ __launch_bounds__(256) void pack_w_kernel(const float* __restrict__ w,
                                                     unsigned short* __restrict__ wb, int n8) {
  int t = blockIdx.x * 256 + threadIdx.x;
  if (t < n8) {
    short8 v = load_f32x8_bf16(w + (size_t)t * 8);
    *(short8*)(wb + (size_t)t * 8) = v;
  }
}

// ---------------- Kernel 0b: pack mask (int32) -> 1 bit/key ----------------
// mask64[(b*Q+q)*32 + p/64], bit (p&63) set = masked-out.
__global__ __launch_bounds__(256) void pack_mask_kernel(const int* __restrict__ mask,
                                                        unsigned long long* __restrict__ mask64) {
  int wave = (blockIdx.x * 256 + threadIdx.x) >> 6;  // 8192 waves
  int lane = threadIdx.x & 63;
  const int NG = BB * QQ * (PP / 64);  // 262144 groups
  for (int g = wave; g < NG; g += 8192) {
    int v = mask[(size_t)g * 64 + lane];
    unsigned long long bits = __ballot(v != 0);
    if (lane == 0) mask64[g] = bits;
  }
}

// ---------------- Kernel 1: input projections (round-9 exact, PASSED) ----------------
template <int NF>
__global__ __launch_bounds__(512) void proj_kernel(
    const float* __restrict__ in, const unsigned short* __restrict__ wb,
    const float* __restrict__ bias,
    unsigned short* __restrict__ out0, unsigned short* __restrict__ out1,
    int mode) {
  int tid = threadIdx.x;
  int wid = tid >> 6, lane = tid & 63;
  int wm = wid >> 2, wn = wid & 3;
  int lr = lane & 15, lk = lane >> 4;
  int m0 = blockIdx.x * 64 + wm * 32;
  int n0 = wn * NF * 16;

  f32x4 acc[2][NF] = {};
  for (int k0 = 0; k0 < 256; k0 += 32) {
    short8 af[2];
    af[0] = load_f32x8_bf16(in + (size_t)(m0 + lr) * 256 + k0 + lk * 8);
    af[1] = load_f32x8_bf16(in + (size_t)(m0 + 16 + lr) * 256 + k0 + lk * 8);
#pragma unroll
    for (int j = 0; j < NF; j++) {
      short8 bfr = *(const short8*)(wb + (size_t)(n0 + j * 16 + lr) * 256 + k0 + lk * 8);
      acc[0][j] = __builtin_amdgcn_mfma_f32_16x16x32_bf16(af[0], bfr, acc[0][j], 0, 0, 0);
      acc[1][j] = __builtin_amdgcn_mfma_f32_16x16x32_bf16(af[1], bfr, acc[1][j], 0, 0, 0);
    }
  }
#pragma unroll
  for (int i = 0; i < 2; i++)
#pragma unroll
    for (int j = 0; j < NF; j++) {
      int n = n0 + j * 16 + lr;  // D col = lane&15
      float bv = bias[n];
      if (mode == 1 && n >= 256) {
        // V path: rows m = m0+i*16+lk*4+{0..3} are 4 consecutive p -> one 8B store
        int n2 = n - 256;
        int p0i = m0 + i * 16 + lk * 4;
        int b = p0i >> 11;
        int p = p0i & 2047;
        unsigned long long w = 0;
#pragma unroll
        for (int r = 0; r < 4; r++)
          w |= (unsigned long long)f2bf(acc[i][j][r] + bv) << (r * 16);
        *(unsigned long long*)(out1 + ((size_t)(b * 8 + (n2 >> 5)) * 32 + (n2 & 31)) * 2048 + p) = w;
      } else {
#pragma unroll
        for (int r = 0; r < 4; r++) {
          int m = m0 + i * 16 + lk * 4 + r;  // D row = 4*(lane>>4)+r
          unsigned short o = f2bf(acc[i][j][r] + bv);
          if (mode == 0) {
            int b = m >> 9, q = m & 511;
            out0[(((size_t)(b * 8 + (n >> 5)) * 512 + q) * 32) + (n & 31)] = o;
          } else {
            int b = m >> 11, p = m & 2047;
            out0[(((size_t)(b * 8 + (n >> 5)) * 2048 + p) * 32) + (n & 31)] = o;
          }
        }
      }
    }
}

// ---------------- Kernel 2: attention (R9 skeleton + load-early pipelining) ----------------
// Structure identical to R9 (passed): 4 waves, LDS-P, in-loop __syncthreads,
// no-max softmax, bitmask, XCD-aware mapping. New (R11-proven mechanism):
// V(i), K(i+1), mask(i+1) are loaded into registers BEFORE the barrier so the
// barrier's vmcnt(0) drain overlaps their latency with the exp phase; PV and
// the next QK^T then run on ready registers.
__global__ __launch_bounds__(256) void attn_kernel(
    const unsigned short* __restrict__ Qb, const unsigned short* __restrict__ Kb,
    const unsigned short* __restrict__ Vt, const unsigned long long* __restrict__ mask64,
    unsigned short* __restrict__ Ob) {
  __shared__ unsigned short Plds[4][16][72];  // per-wave P tile (wave-private)
  int bid = blockIdx.x;
  int xcd = bid & 7, sg = bid >> 3;
  int bh = xcd * 16 + (sg >> 3);
  int qt = sg & 7;
  int b = bh >> 3, h = bh & 7;
  int tid = threadIdx.x, wid = tid >> 6, lane = tid & 63;
  int lr = lane & 15, lk = lane >> 4;
  int qbase = qt * 64 + wid * 16;
  const float sl2e = 0.17677669529663687f * 1.4426950408889634f;  // scale*log2(e)

  short8 qa = *(const short8*)(Qb + ((size_t)bh * QQ + qbase + lr) * 32 + lk * 8);

  float psum[4] = {0.f, 0.f, 0.f, 0.f};  // row lk*4+r, this lane's keys {f*16+lr}
  f32x4 acc[2] = {};

  const unsigned short* Kbase = Kb + (size_t)bh * PP * 32;
  const unsigned short* Vbase = Vt + (size_t)bh * 32 * PP;
  const unsigned long long* mbase = mask64 + ((size_t)b * QQ + qbase) * (PP / 64);

  // prologue: K chunk 0 + mask chunk 0 in registers
  short8 kb[4];
#pragma unroll
  for (int f = 0; f < 4; f++)
    kb[f] = *(const short8*)(Kbase + (size_t)(f * 16 + lr) * 32 + lk * 8);
  unsigned long long m64[4];
#pragma unroll
  for (int r = 0; r < 4; r++)
    m64[r] = mbase[(size_t)(lk * 4 + r) * (PP / 64)];

  for (int p0 = 0; p0 < PP; p0 += 64) {
    // S = Q*K^T for 16 q x 64 keys (4 MFMAs) from registers
    f32x4 s[4];
#pragma unroll
    for (int f = 0; f < 4; f++) {
      f32x4 z = {};
      s[f] = __builtin_amdgcn_mfma_f32_16x16x32_bf16(qa, kb[f], z, 0, 0, 0);
    }
    // issue loads early: V(this chunk), K(next), mask(next) — all consumed
    // after the barrier; latency hides under the exp phase + barrier drain.
    int pn = (p0 + 64) & (PP - 1);  // wrap: harmless in-bounds read
    short8 vb[2][2];
#pragma unroll
    for (int kc = 0; kc < 2; kc++)
#pragma unroll
      for (int dhf = 0; dhf < 2; dhf++)
        vb[kc][dhf] = *(const short8*)(Vbase + (size_t)(dhf * 16 + lr) * PP + p0 + kc * 32 + lk * 8);
#pragma unroll
    for (int f = 0; f < 4; f++)
      kb[f] = *(const short8*)(Kbase + (size_t)(pn + f * 16 + lr) * 32 + lk * 8);
    unsigned long long m64n[4];
#pragma unroll
    for (int r = 0; r < 4; r++)
      m64n[r] = mbase[(size_t)(lk * 4 + r) * (PP / 64) + (pn >> 6)];
    // p = exp2(s*scale*log2e); masked -> exactly 0. No max subtraction.
#pragma unroll
    for (int f = 0; f < 4; f++)
#pragma unroll
      for (int r = 0; r < 4; r++) {
        int masked = (int)((m64[r] >> (f * 16 + lr)) & 1ull);
        float p = exp2f(s[f][r] * sl2e);
        p = masked ? 0.f : p;
        psum[r] += p;
        Plds[wid][lk * 4 + r][f * 16 + lr] = f2bf(p);
      }
#pragma unroll
    for (int r = 0; r < 4; r++) m64[r] = m64n[r];
    __syncthreads();  // proven-required; drains all loads usefully here
    // PV: acc += P[16x64] * V[64x32] — LDS reads + ready V registers
#pragma unroll
    for (int kc = 0; kc < 2; kc++) {
      short8 pa = *(const short8*)&Plds[wid][lr][kc * 32 + lk * 8];
#pragma unroll
      for (int dhf = 0; dhf < 2; dhf++)
        acc[dhf] = __builtin_amdgcn_mfma_f32_16x16x32_bf16(pa, vb[kc][dhf], acc[dhf], 0, 0, 0);
    }
  }
  // single final reduce: psum[r] over the 16 lr lanes (width-16 butterfly)
#pragma unroll
  for (int r = 0; r < 4; r++) {
#pragma unroll
    for (int d = 1; d < 16; d <<= 1) psum[r] += __shfl_xor(psum[r], d, 64);
  }
  // normalize + write O bf16 [B,Q,256]
#pragma unroll
  for (int dhf = 0; dhf < 2; dhf++)
#pragma unroll
    for (int r = 0; r < 4; r++) {
      int q = qbase + lk * 4 + r;
      float o = acc[dhf][r] / psum[r];
      Ob[((size_t)b * QQ + q) * 256 + h * 32 + dhf * 16 + lr] = f2bf(o);
    }
}

// ---------------- Kernel 3: out-proj + bias + residual + LayerNorm (round-9 exact) ----------------
__global__ __launch_bounds__(256) void outln_kernel(
    const unsigned short* __restrict__ Ob, const float* __restrict__ out_w,
    const float* __restrict__ out_b, const float* __restrict__ queries,
    const float* __restrict__ ln_g, const float* __restrict__ ln_b,
    float* __restrict__ out) {
  __shared__ float rowbuf[16][260];
  int mt = blockIdx.x;
  int tid = threadIdx.x, wid = tid >> 6, lane = tid & 63;
  int lr = lane & 15, lk = lane >> 4;
  int m0 = mt * 16;
  f32x4 acc[4] = {};
  for (int k0 = 0; k0 < 256; k0 += 32) {
    short8 af = *(const short8*)(Ob + (size_t)(m0 + lr) * 256 + k0 + lk * 8);
#pragma unroll
    for (int j = 0; j < 4; j++) {
      short8 bfr = load_f32x8_bf16(out_w + (size_t)(wid * 64 + j * 16 + lr) * 256 + k0 + lk * 8);
      acc[j] = __builtin_amdgcn_mfma_f32_16x16x32_bf16(af, bfr, acc[j], 0, 0, 0);
    }
  }
#pragma unroll
  for (int j = 0; j < 4; j++) {
    int n = wid * 64 + j * 16 + lr;
    float bv = out_b[n];
#pragma unroll
    for (int r = 0; r < 4; r++) {
      int m = m0 + lk * 4 + r;
      rowbuf[lk * 4 + r][n] = acc[j][r] + bv + queries[(size_t)m * 256 + n];
    }
  }
  __syncthreads();
  int row = tid >> 4, seg = tid & 15;
  float s1 = 0.f, s2 = 0.f, vals[16];
#pragma unroll
  for (int c = 0; c < 16; c++) {
    float v = rowbuf[row][seg * 16 + c];
    vals[c] = v; s1 += v; s2 += v * v;
  }
#pragma unroll
  for (int d = 1; d < 16; d <<= 1) {
    s1 += __shfl_xor(s1, d, 64);
    s2 += __shfl_xor(s2, d, 64);
  }
  float mean = s1 * (1.f / 256.f);
  float var = s2 * (1.f / 256.f) - mean * mean;
  float rstd = rsqrtf(var + 1e-5f);
  int m = m0 + row;
#pragma unroll
  for (int c = 0; c < 16; c++) {
    int col = seg * 16 + c;
    out[(size_t)m * 256 + col] = (vals[c] - mean) * rstd * ln_g[col] + ln_b[col];
  }
}

extern "C" void kernel_launch(void* const* d_in, const int* in_sizes, int n_in,
                              void* d_out, int out_size, void* d_ws, size_t ws_size,
                              hipStream_t stream) {
  const float* sources  = (const float*)d_in[0];
  const float* queries  = (const float*)d_in[1];
  const int* attn_mask  = (const int*)d_in[2];
  const float* in_proj_w = (const float*)d_in[3];
  const float* in_proj_b = (const float*)d_in[4];
  const float* out_w = (const float*)d_in[5];
  const float* out_b = (const float*)d_in[6];
  const float* ln_g  = (const float*)d_in[7];
  const float* ln_b  = (const float*)d_in[8];
  float* out = (float*)d_out;

  // workspace layout (shorts) — identical footprint to rounds 3/6/8/9 (passed):
  unsigned short* base = (unsigned short*)d_ws;
  unsigned long long* mask64 = (unsigned long long*)d_ws;          // 2 MB
  unsigned short* Qb = base + 1048576;                             // [B,H,Q,32]
  unsigned short* Kb = Qb + 2097152;                               // [B,H,P,32]
  unsigned short* Vt = Kb + 8388608;                               // [B,H,32,P]
  unsigned short* Ob = Vt + 8388608;                               // [B,Q,256]
  unsigned short* Wb = Ob + 2097152;                               // in_proj_w bf16

  dim3 b256(256), b512(512);
  pack_w_kernel<<<96, b256, 0, stream>>>(in_proj_w, Wb, 768 * 256 / 8);
  pack_mask_kernel<<<2048, b256, 0, stream>>>(attn_mask, mask64);
  proj_kernel<4><<<128, b512, 0, stream>>>(queries, Wb, in_proj_b, Qb, nullptr, 0);
  proj_kernel<8><<<512, b512, 0, stream>>>(sources, Wb + 256 * 256, in_proj_b + 256, Kb, Vt, 1);
  attn_kernel<<<1024, b256, 0, stream>>>(Qb, Kb, Vt, mask64, Ob);
  outln_kernel<<<512, b256, 0, stream>>>(Ob, out_w, out_b, queries, ln_g, ln_b, out);
}

// Round 16
// 218.295 us; speedup vs baseline: 1.0190x; 1.0181x over previous
//
#include <hip/hip_runtime.h>

// B=16, Q=512, P=2048, D=256, H=8, DH=32
#define BB 16
#define QQ 512
#define PP 2048
#define DD 256
#define HH 8
#define DH 32

typedef __attribute__((ext_vector_type(8))) short short8;
typedef __attribute__((ext_vector_type(4))) float f32x4;

static __device__ __forceinline__ unsigned short f2bf(float f) {
  union { float f; unsigned u; } v; v.f = f;
  unsigned u = v.u;
  unsigned r = (u + 0x7FFFu + ((u >> 16) & 1u)) >> 16;  // RNE
  return (unsigned short)r;
}

static __device__ __forceinline__ short8 load_f32x8_bf16(const float* p) {
  const float4* p4 = (const float4*)p;
  float4 a = p4[0], b = p4[1];
  short8 r;
  r[0] = (short)f2bf(a.x); r[1] = (short)f2bf(a.y);
  r[2] = (short)f2bf(a.z); r[3] = (short)f2bf(a.w);
  r[4] = (short)f2bf(b.x); r[5] = (short)f2bf(b.y);
  r[6] = (short)f2bf(b.z); r[7] = (short)f2bf(b.w);
  return r;
}

// ---------------- Kernel 0a: pack in_proj_w (768x256 f32) -> bf16 ----------------
__global__ __launch_bounds__(256) void pack_w_kernel(const float* __restrict__ w,
                                                     unsigned short* __restrict__ wb, int n8) {
  int t = blockIdx.x * 256 + threadIdx.x;
  if (t < n8) {
    short8 v = load_f32x8_bf16(w + (size_t)t * 8);
    *(short8*)(wb + (size_t)t * 8) = v;
  }
}

// ---------------- Kernel 0b: pack mask (int32) -> 1 bit/key ----------------
// mask64[(b*Q+q)*32 + p/64], bit (p&63) set = masked-out.
__global__ __launch_bounds__(256) void pack_mask_kernel(const int* __restrict__ mask,
                                                        unsigned long long* __restrict__ mask64) {
  int wave = (blockIdx.x * 256 + threadIdx.x) >> 6;  // 8192 waves
  int lane = threadIdx.x & 63;
  const int NG = BB * QQ * (PP / 64);  // 262144 groups
  for (int g = wave; g < NG; g += 8192) {
    int v = mask[(size_t)g * 64 + lane];
    unsigned long long bits = __ballot(v != 0);
    if (lane == 0) mask64[g] = bits;
  }
}

// ---------------- Kernel 1: input projections (round-9 exact, PASSED) ----------------
template <int NF>
__global__ __launch_bounds__(512) void proj_kernel(
    const float* __restrict__ in, const unsigned short* __restrict__ wb,
    const float* __restrict__ bias,
    unsigned short* __restrict__ out0, unsigned short* __restrict__ out1,
    int mode) {
  int tid = threadIdx.x;
  int wid = tid >> 6, lane = tid & 63;
  int wm = wid >> 2, wn = wid & 3;
  int lr = lane & 15, lk = lane >> 4;
  int m0 = blockIdx.x * 64 + wm * 32;
  int n0 = wn * NF * 16;

  f32x4 acc[2][NF] = {};
  for (int k0 = 0; k0 < 256; k0 += 32) {
    short8 af[2];
    af[0] = load_f32x8_bf16(in + (size_t)(m0 + lr) * 256 + k0 + lk * 8);
    af[1] = load_f32x8_bf16(in + (size_t)(m0 + 16 + lr) * 256 + k0 + lk * 8);
#pragma unroll
    for (int j = 0; j < NF; j++) {
      short8 bfr = *(const short8*)(wb + (size_t)(n0 + j * 16 + lr) * 256 + k0 + lk * 8);
      acc[0][j] = __builtin_amdgcn_mfma_f32_16x16x32_bf16(af[0], bfr, acc[0][j], 0, 0, 0);
      acc[1][j] = __builtin_amdgcn_mfma_f32_16x16x32_bf16(af[1], bfr, acc[1][j], 0, 0, 0);
    }
  }
#pragma unroll
  for (int i = 0; i < 2; i++)
#pragma unroll
    for (int j = 0; j < NF; j++) {
      int n = n0 + j * 16 + lr;  // D col = lane&15
      float bv = bias[n];
      if (mode == 1 && n >= 256) {
        // V path: rows m = m0+i*16+lk*4+{0..3} are 4 consecutive p -> one 8B store
        int n2 = n - 256;
        int p0i = m0 + i * 16 + lk * 4;
        int b = p0i >> 11;
        int p = p0i & 2047;
        unsigned long long w = 0;
#pragma unroll
        for (int r = 0; r < 4; r++)
          w |= (unsigned long long)f2bf(acc[i][j][r] + bv) << (r * 16);
        *(unsigned long long*)(out1 + ((size_t)(b * 8 + (n2 >> 5)) * 32 + (n2 & 31)) * 2048 + p) = w;
      } else {
#pragma unroll
        for (int r = 0; r < 4; r++) {
          int m = m0 + i * 16 + lk * 4 + r;  // D row = 4*(lane>>4)+r
          unsigned short o = f2bf(acc[i][j][r] + bv);
          if (mode == 0) {
            int b = m >> 9, q = m & 511;
            out0[(((size_t)(b * 8 + (n >> 5)) * 512 + q) * 32) + (n & 31)] = o;
          } else {
            int b = m >> 11, p = m & 2047;
            out0[(((size_t)(b * 8 + (n >> 5)) * 2048 + p) * 32) + (n & 31)] = o;
          }
        }
      }
    }
}

// ---------------- Kernel 2: attention (R9 body; 2 waves/block, 2048 blocks) ----------------
// Same dataflow/sync/numerics as R9 (passed 4x): LDS-P tile, in-loop
// __syncthreads, no-max softmax, bitmask, XCD-aware mapping. Only the
// grid/block geometry changes: 2-wave blocks -> 8 independent barrier-groups
// per CU instead of 4 convoyed 4-wave groups; blockDim=128 keeps a true
// s_barrier (not elidable as single-wave).
__global__ __launch_bounds__(128) void attn_kernel(
    const unsigned short* __restrict__ Qb, const unsigned short* __restrict__ Kb,
    const unsigned short* __restrict__ Vt, const unsigned long long* __restrict__ mask64,
    unsigned short* __restrict__ Ob) {
  __shared__ unsigned short Plds[2][16][72];  // per-wave P tile (wave-private)
  int bid = blockIdx.x;                        // 2048 blocks
  int xcd = bid & 7, idx = bid >> 3;           // idx in [0,256)
  int bh = xcd * 16 + (idx >> 4);              // 16 heads per XCD
  int qt = idx & 15;                           // 16 q-tiles of 32 rows
  int b = bh >> 3, h = bh & 7;
  int tid = threadIdx.x, wid = tid >> 6, lane = tid & 63;
  int lr = lane & 15, lk = lane >> 4;
  int qbase = qt * 32 + wid * 16;
  const float scale = 0.17677669529663687f;  // 1/sqrt(32)

  short8 qa = *(const short8*)(Qb + ((size_t)bh * QQ + qbase + lr) * 32 + lk * 8);

  float psum[4] = {0.f, 0.f, 0.f, 0.f};  // row lk*4+r, this lane's keys {f*16+lr}
  f32x4 acc[2] = {};

  const unsigned short* Kbase = Kb + (size_t)bh * PP * 32;
  const unsigned short* Vbase = Vt + (size_t)bh * 32 * PP;
  const unsigned long long* mbase = mask64 + ((size_t)b * QQ + qbase) * (PP / 64);

  for (int p0 = 0; p0 < PP; p0 += 64) {
    // S = Q*K^T for 16 q x 64 keys (4 MFMAs)
    f32x4 s[4];
#pragma unroll
    for (int f = 0; f < 4; f++) {
      short8 kb = *(const short8*)(Kbase + (size_t)(p0 + f * 16 + lr) * 32 + lk * 8);
      f32x4 z = {};
      s[f] = __builtin_amdgcn_mfma_f32_16x16x32_bf16(qa, kb, z, 0, 0, 0);
    }
    // bit-mask (q row = lk*4+r, key bit = f*16+lr)
    unsigned long long m64[4];
#pragma unroll
    for (int r = 0; r < 4; r++)
      m64[r] = mbase[(size_t)(lk * 4 + r) * (PP / 64) + (p0 >> 6)];
    // p = exp(s*scale); masked -> exactly 0. No max subtraction.
#pragma unroll
    for (int f = 0; f < 4; f++)
#pragma unroll
      for (int r = 0; r < 4; r++) {
        int masked = (int)((m64[r] >> (f * 16 + lr)) & 1ull);
        float p = __expf(s[f][r] * scale);
        p = masked ? 0.f : p;
        psum[r] += p;
        Plds[wid][lk * 4 + r][f * 16 + lr] = f2bf(p);
      }
    __syncthreads();  // order P writes before PV reads (proven-required)
    // PV: acc += P[16x64] * V[64x32]
#pragma unroll
    for (int kc = 0; kc < 2; kc++) {
      short8 pa = *(const short8*)&Plds[wid][lr][kc * 32 + lk * 8];
#pragma unroll
      for (int dhf = 0; dhf < 2; dhf++) {
        short8 vb = *(const short8*)(Vbase + (size_t)(dhf * 16 + lr) * PP + p0 + kc * 32 + lk * 8);
        acc[dhf] = __builtin_amdgcn_mfma_f32_16x16x32_bf16(pa, vb, acc[dhf], 0, 0, 0);
      }
    }
  }
  // single final reduce: psum[r] over the 16 lr lanes (width-16 butterfly)
#pragma unroll
  for (int r = 0; r < 4; r++) {
#pragma unroll
    for (int d = 1; d < 16; d <<= 1) psum[r] += __shfl_xor(psum[r], d, 64);
  }
  // normalize + write O bf16 [B,Q,256]
#pragma unroll
  for (int dhf = 0; dhf < 2; dhf++)
#pragma unroll
    for (int r = 0; r < 4; r++) {
      int q = qbase + lk * 4 + r;
      float o = acc[dhf][r] / psum[r];
      Ob[((size_t)b * QQ + q) * 256 + h * 32 + dhf * 16 + lr] = f2bf(o);
    }
}

// ---------------- Kernel 3: out-proj + residual + LayerNorm (round-9 exact, PASSED) ----------------
__global__ __launch_bounds__(256) void outln_kernel(
    const unsigned short* __restrict__ Ob, const float* __restrict__ out_w,
    const float* __restrict__ out_b, const float* __restrict__ queries,
    const float* __restrict__ ln_g, const float* __restrict__ ln_b,
    float* __restrict__ out) {
  __shared__ float rowbuf[16][260];
  int mt = blockIdx.x;
  int tid = threadIdx.x, wid = tid >> 6, lane = tid & 63;
  int lr = lane & 15, lk = lane >> 4;
  int m0 = mt * 16;
  f32x4 acc[4] = {};
  for (int k0 = 0; k0 < 256; k0 += 32) {
    short8 af = *(const short8*)(Ob + (size_t)(m0 + lr) * 256 + k0 + lk * 8);
#pragma unroll
    for (int j = 0; j < 4; j++) {
      short8 bfr = load_f32x8_bf16(out_w + (size_t)(wid * 64 + j * 16 + lr) * 256 + k0 + lk * 8);
      acc[j] = __builtin_amdgcn_mfma_f32_16x16x32_bf16(af, bfr, acc[j], 0, 0, 0);
    }
  }
#pragma unroll
  for (int j = 0; j < 4; j++) {
    int n = wid * 64 + j * 16 + lr;
    float bv = out_b[n];
#pragma unroll
    for (int r = 0; r < 4; r++) {
      int m = m0 + lk * 4 + r;
      rowbuf[lk * 4 + r][n] = acc[j][r] + bv + queries[(size_t)m * 256 + n];
    }
  }
  __syncthreads();
  int row = tid >> 4, seg = tid & 15;
  float s1 = 0.f, s2 = 0.f, vals[16];
#pragma unroll
  for (int c = 0; c < 16; c++) {
    float v = rowbuf[row][seg * 16 + c];
    vals[c] = v; s1 += v; s2 += v * v;
  }
#pragma unroll
  for (int d = 1; d < 16; d <<= 1) {
    s1 += __shfl_xor(s1, d, 64);
    s2 += __shfl_xor(s2, d, 64);
  }
  float mean = s1 * (1.f / 256.f);
  float var = s2 * (1.f / 256.f) - mean * mean;
  float rstd = rsqrtf(var + 1e-5f);
  int m = m0 + row;
#pragma unroll
  for (int c = 0; c < 16; c++) {
    int col = seg * 16 + c;
    out[(size_t)m * 256 + col] = (vals[c] - mean) * rstd * ln_g[col] + ln_b[col];
  }
}

extern "C" void kernel_launch(void* const* d_in, const int* in_sizes, int n_in,
                              void* d_out, int out_size, void* d_ws, size_t ws_size,
                              hipStream_t stream) {
  const float* sources  = (const float*)d_in[0];
  const float* queries  = (const float*)d_in[1];
  const int* attn_mask  = (const int*)d_in[2];
  const float* in_proj_w = (const float*)d_in[3];
  const float* in_proj_b = (const float*)d_in[4];
  const float* out_w = (const float*)d_in[5];
  const float* out_b = (const float*)d_in[6];
  const float* ln_g  = (const float*)d_in[7];
  const float* ln_b  = (const float*)d_in[8];
  float* out = (float*)d_out;

  // workspace layout (shorts) — R3/R9 proven footprint (44,433,408 B).
  // HARD CEILING: extending past this corrupted adjacent memory (R4/5/14/15).
  unsigned short* base = (unsigned short*)d_ws;
  unsigned long long* mask64 = (unsigned long long*)d_ws;          // 2 MB
  unsigned short* Qb = base + 1048576;                             // [B,H,Q,32]
  unsigned short* Kb = Qb + 2097152;                               // [B,H,P,32]
  unsigned short* Vt = Kb + 8388608;                               // [B,H,32,P]
  unsigned short* Ob = Vt + 8388608;                               // [B,Q,256]
  unsigned short* Wb = Ob + 2097152;                               // in_proj_w bf16 (768x256)

  dim3 b128(128), b256(256), b512(512);
  pack_w_kernel<<<96, b256, 0, stream>>>(in_proj_w, Wb, 768 * 256 / 8);
  pack_mask_kernel<<<2048, b256, 0, stream>>>(attn_mask, mask64);
  proj_kernel<4><<<128, b512, 0, stream>>>(queries, Wb, in_proj_b, Qb, nullptr, 0);
  proj_kernel<8><<<512, b512, 0, stream>>>(sources, Wb + 256 * 256, in_proj_b + 256, Kb, Vt, 1);
  attn_kernel<<<2048, b128, 0, stream>>>(Qb, Kb, Vt, mask64, Ob);
  outln_kernel<<<512, b256, 0, stream>>>(Ob, out_w, out_b, queries, ln_g, ln_b, out);
}